// Round 6
// baseline (75.273 us; speedup 1.0000x reference)
//
#include <hip/hip_runtime.h>

typedef float f32x4 __attribute__((ext_vector_type(4)));
typedef _Float16 f16x8 __attribute__((ext_vector_type(8)));
typedef __fp16 fp16x2 __attribute__((ext_vector_type(2)));

#define NEG_SLOPE 0.2f
#define MASK_EPS 1e-8f

// ---------------------------------------------------------------------------
// Kernel 1: Wh = h @ W; writes WhT (f16, [b][d=128][i=512]) via LDS transpose,
// plus scores sI_T/sJ_T ([b][h][i], fp32).  (unchanged)
// ---------------------------------------------------------------------------
__global__ __launch_bounds__(256) void gat_wh_kernel(
    const float* __restrict__ h, const float* __restrict__ W,
    const float* __restrict__ a, _Float16* __restrict__ whT,
    float* __restrict__ sIT, float* __restrict__ sJT) {
  __shared__ float hS[8][128];
  __shared__ _Float16 trS[128][16];
  const int tid = threadIdx.x;
  const int row0 = blockIdx.x * 8;

  {
    int r = tid >> 5, c4 = (tid & 31) << 2;
    *(float4*)&hS[r][c4] = *(const float4*)&h[(size_t)(row0 + r) * 128 + c4];
  }
  __syncthreads();

  const int rowl = tid >> 5;
  const int cidx = tid & 31;
  const int c0 = cidx << 2;

  float4 acc = {0.f, 0.f, 0.f, 0.f};
#pragma unroll 8
  for (int k = 0; k < 128; ++k) {
    float hv = hS[rowl][k];
    float4 w4 = *(const float4*)&W[k * 128 + c0];
    acc.x = fmaf(hv, w4.x, acc.x);
    acc.y = fmaf(hv, w4.y, acc.y);
    acc.z = fmaf(hv, w4.z, acc.z);
    acc.w = fmaf(hv, w4.w, acc.w);
  }

  const int row = row0 + rowl;
  const int bb = row >> 9;
  const int nloc = row & 511;

  const int head = cidx >> 3;
  const int dl = c0 & 31;
  const float* asrc = &a[head * 64];
  const float* adst = &a[head * 64 + 32];
  float pi = acc.x * asrc[dl] + acc.y * asrc[dl + 1] + acc.z * asrc[dl + 2] + acc.w * asrc[dl + 3];
  float pj = acc.x * adst[dl] + acc.y * adst[dl + 1] + acc.z * adst[dl + 2] + acc.w * adst[dl + 3];
#pragma unroll
  for (int off = 1; off < 8; off <<= 1) {
    pi += __shfl_xor(pi, off, 64);
    pj += __shfl_xor(pj, off, 64);
  }
  if ((cidx & 7) == 0) {
    sIT[bb * 2048 + head * 512 + nloc] = pi;
    sJT[bb * 2048 + head * 512 + nloc] = pj;
  }

  trS[c0 + 0][rowl] = (_Float16)acc.x;
  trS[c0 + 1][rowl] = (_Float16)acc.y;
  trS[c0 + 2][rowl] = (_Float16)acc.z;
  trS[c0 + 3][rowl] = (_Float16)acc.w;
  __syncthreads();

  if (tid < 128) {
    const int d = tid;
    const int i0 = row0 & 511;
    float4 v = *(const float4*)&trS[d][0];
    *(float4*)&whT[((size_t)(row0 >> 9) * 128 + d) * 512 + i0] = v;
  }
}

// ---------------------------------------------------------------------------
// Kernel 2: pack (adj > eps) into transposed bitmask maskT[b][j][16 u32]
// (bit i%32 of word i/32). Coalesced adj reads (64 consecutive j per wave).
// Block = (b, j-tile 64, i-chunk 128); thread = (iw4, jl).
// ---------------------------------------------------------------------------
__global__ __launch_bounds__(256) void gat_mask_kernel(
    const float* __restrict__ adj, unsigned* __restrict__ maskT) {
  const int b = blockIdx.x, jt = blockIdx.y, ic = blockIdx.z;
  const int tid = threadIdx.x;
  const int jl = tid & 63;
  const int iw4 = tid >> 6;            // 0..3
  const int j = jt * 64 + jl;
  const int i0 = ic * 128 + iw4 * 32;
  const float* ap = adj + (size_t)b * 512 * 512 + (size_t)i0 * 512 + j;
  unsigned w = 0;
#pragma unroll
  for (int i = 0; i < 32; ++i)
    w |= (ap[(size_t)i * 512] > MASK_EPS ? 1u : 0u) << i;
  maskT[((size_t)b * 512 + j) * 16 + ic * 4 + iw4] = w;
}

// ---------------------------------------------------------------------------
// Kernel 3: attention+aggregate. Zero LDS, zero barriers, zero adj traffic:
// lane preloads its 16 mask words (64B); main loop is L2-resident si/WhT
// fragment loads + exp/cvt VALU + MFMA 16x16x32. Fully unrolled t-loop.
// ---------------------------------------------------------------------------
__global__ __launch_bounds__(256, 4) void gat_attn_kernel(
    const unsigned* __restrict__ maskT, const _Float16* __restrict__ whT,
    const float* __restrict__ sIT, const float* __restrict__ sJT,
    float* __restrict__ out) {
  const int tid = threadIdx.x;
  const int b = blockIdx.x;            // 0..31
  const int j0 = blockIdx.y * 16;      // 32 tiles
  const int wv = tid >> 6;             // wave = head
  const int lane = tid & 63;
  const int nl = lane & 15;
  const int ig = lane >> 4;

  const float sj = sJT[b * 2048 + wv * 512 + j0 + nl];

  const unsigned* mP = maskT + ((size_t)b * 512 + j0 + nl) * 16;
  uint4 mA = *(const uint4*)(mP);
  uint4 mB = *(const uint4*)(mP + 4);
  uint4 mC = *(const uint4*)(mP + 8);
  uint4 mD = *(const uint4*)(mP + 12);
  const unsigned mw[16] = {mA.x, mA.y, mA.z, mA.w, mB.x, mB.y, mB.z, mB.w,
                           mC.x, mC.y, mC.z, mC.w, mD.x, mD.y, mD.z, mD.w};

  const _Float16* whP = whT + (size_t)b * 128 * 512 + (size_t)(wv * 32 + nl) * 512 + ig * 8;
  const float* siP = sIT + b * 2048 + wv * 512 + ig * 8;

  f32x4 acc0 = {0.f, 0.f, 0.f, 0.f};
  f32x4 acc1 = {0.f, 0.f, 0.f, 0.f};
  float l = 0.f;

#pragma unroll
  for (int t = 0; t < 8; ++t) {
#pragma unroll
    for (int ks = 0; ks < 2; ++ks) {
      f32x4 sA = *(const f32x4*)(siP + t * 64 + ks * 32);
      f32x4 sB = *(const f32x4*)(siP + t * 64 + ks * 32 + 4);
      const f16x8 bf0 = *(const f16x8*)(whP + t * 64 + ks * 32);
      const f16x8 bf1 = *(const f16x8*)(whP + 16 * 512 + t * 64 + ks * 32);
      const unsigned bits = (mw[t * 2 + ks] >> (ig * 8)) & 0xffu;

      float si[8] = {sA.x, sA.y, sA.z, sA.w, sB.x, sB.y, sB.z, sB.w};
      float p[8];
#pragma unroll
      for (int r = 0; r < 8; ++r) {
        float e = si[r] + sj;
        e = e >= 0.f ? e : NEG_SLOPE * e;
        p[r] = (bits & (1u << r)) ? __expf(e) : 0.f;
      }
      l += ((p[0] + p[1]) + (p[2] + p[3])) + ((p[4] + p[5]) + (p[6] + p[7]));

      union { fp16x2 h2[4]; f16x8 v; } af;
#pragma unroll
      for (int q = 0; q < 4; ++q)
        af.h2[q] = __builtin_amdgcn_cvt_pkrtz(p[2 * q], p[2 * q + 1]);

      acc0 = __builtin_amdgcn_mfma_f32_16x16x32_f16(af.v, bf0, acc0, 0, 0, 0);
      acc1 = __builtin_amdgcn_mfma_f32_16x16x32_f16(af.v, bf1, acc1, 0, 0, 0);
    }
  }

  // reduce l over the 4 ig-slices -> every lane has l for j = j0 + nl
  l += __shfl_xor(l, 16, 64);
  l += __shfl_xor(l, 32, 64);

  // D layout: row(m=j_local) = 4*ig + reg, col(n=d_lo) = nl
  float* outB = out + ((size_t)b * 512 + j0) * 128 + wv * 32;
#pragma unroll
  for (int reg = 0; reg < 4; ++reg) {
    const int jr = 4 * ig + reg;
    const float rl = 1.0f / __shfl(l, jr, 64);
    outB[(size_t)jr * 128 + nl]      = acc0[reg] * rl;
    outB[(size_t)jr * 128 + 16 + nl] = acc1[reg] * rl;
  }
}

extern "C" void kernel_launch(void* const* d_in, const int* in_sizes, int n_in,
                              void* d_out, int out_size, void* d_ws, size_t ws_size,
                              hipStream_t stream) {
  const float* h = (const float*)d_in[0];     // (32, 512, 128)
  const float* adj = (const float*)d_in[1];   // (32, 512, 512)
  const float* W = (const float*)d_in[2];     // (128, 128)
  const float* a = (const float*)d_in[3];     // (4, 64)
  float* out = (float*)d_out;                 // (32, 512, 128)

  _Float16* whT = (_Float16*)d_ws;                      // 4 MB
  float* sIT = (float*)(whT + (size_t)32 * 128 * 512);  // 256 KB
  float* sJT = sIT + (size_t)32 * 4 * 512;              // 256 KB
  unsigned* maskT = (unsigned*)(sJT + (size_t)32 * 4 * 512);  // 1 MB

  gat_wh_kernel<<<dim3(2048), dim3(256), 0, stream>>>(h, W, a, whT, sIT, sJT);
  gat_mask_kernel<<<dim3(32, 8, 4), dim3(256), 0, stream>>>(adj, maskT);
  gat_attn_kernel<<<dim3(32, 32), dim3(256), 0, stream>>>(maskT, whT, sIT, sJT, out);
}

// Round 7
// 51.654 us; speedup vs baseline: 1.4573x; 1.4573x over previous
//
#include <hip/hip_runtime.h>

typedef float f32x4 __attribute__((ext_vector_type(4)));
typedef _Float16 f16x8 __attribute__((ext_vector_type(8)));
typedef __fp16 fp16x2 __attribute__((ext_vector_type(2)));

#define NEG_SLOPE 0.2f
#define MASK_EPS 1e-8f

// ---------------------------------------------------------------------------
// Kernel 1: pack (adj > eps) into transposed bitmask maskT[b][j][16 u32]
// (bit i%32 of word i/32). Coalesced adj reads. Blocks with jt==0&&ic==0 also
// convert W (f32 [k][n]) -> wTf16 (f16 [n][k]) for the MFMA kernels.
// ---------------------------------------------------------------------------
__global__ __launch_bounds__(256) void gat_mask_kernel(
    const float* __restrict__ adj, unsigned* __restrict__ maskT,
    const float* __restrict__ W, _Float16* __restrict__ wTf16) {
  const int b = blockIdx.x, jt = blockIdx.y, ic = blockIdx.z;
  const int tid = threadIdx.x;
  const int jl = tid & 63;
  const int iw4 = tid >> 6;            // 0..3
  const int j = jt * 64 + jl;
  const int i0 = ic * 128 + iw4 * 32;
  const float* ap = adj + (size_t)b * 512 * 512 + (size_t)i0 * 512 + j;
  unsigned w = 0;
#pragma unroll
  for (int i = 0; i < 32; ++i)
    w |= (ap[(size_t)i * 512] > MASK_EPS ? 1u : 0u) << i;
  maskT[((size_t)b * 512 + j) * 16 + ic * 4 + iw4] = w;

  if (jt == 0 && ic == 0) {            // 32 blocks: W transpose+convert
    const int k = b * 4 + (tid >> 6);  // 4 k-rows per block
    const int n = tid & 63;
    wTf16[(n) * 128 + k]      = (_Float16)W[k * 128 + n];
    wTf16[(n + 64) * 128 + k] = (_Float16)W[k * 128 + n + 64];
  }
}

// ---------------------------------------------------------------------------
// Kernel 2: Wh = h @ W via f16 MFMA. Zero LDS, zero barriers.
// Block = 16 rows; 4 waves = 4 heads (n-quarters of 32 cols).
// A-frag: h f32 direct loads + cvt_pkrtz; B-frag: wTf16 16B loads (L1-hot).
// Epilogue: per-head scores s_i/s_j from f32 acc (shuffle-reduce over nl),
// whT written as packed f16 (8B = 4 consecutive i per store).
// ---------------------------------------------------------------------------
__global__ __launch_bounds__(256, 4) void gat_wh_mfma(
    const float* __restrict__ h, const _Float16* __restrict__ wTf16,
    const float* __restrict__ a, _Float16* __restrict__ whT,
    float* __restrict__ sIT, float* __restrict__ sJT) {
  const int tid = threadIdx.x;
  const int bid = blockIdx.x;          // 0..1023, 16 rows each
  const int w = tid >> 6;              // wave = head
  const int lane = tid & 63;
  const int nl = lane & 15;
  const int ig = lane >> 4;
  const int row0 = bid * 16;
  const int bb = row0 >> 9;
  const int iloc = row0 & 511;

  const float* hP = h + (size_t)(row0 + nl) * 128 + ig * 8;
  const _Float16* wP0 = wTf16 + (size_t)(w * 32 + nl) * 128 + ig * 8;
  const _Float16* wP1 = wTf16 + (size_t)(w * 32 + 16 + nl) * 128 + ig * 8;

  f32x4 acc0 = {0.f, 0.f, 0.f, 0.f};
  f32x4 acc1 = {0.f, 0.f, 0.f, 0.f};

#pragma unroll
  for (int kt = 0; kt < 4; ++kt) {
    f32x4 ha = *(const f32x4*)(hP + kt * 32);
    f32x4 hb = *(const f32x4*)(hP + kt * 32 + 4);
    union { fp16x2 h2[4]; f16x8 v; } af;
    af.h2[0] = __builtin_amdgcn_cvt_pkrtz(ha.x, ha.y);
    af.h2[1] = __builtin_amdgcn_cvt_pkrtz(ha.z, ha.w);
    af.h2[2] = __builtin_amdgcn_cvt_pkrtz(hb.x, hb.y);
    af.h2[3] = __builtin_amdgcn_cvt_pkrtz(hb.z, hb.w);
    const f16x8 b0 = *(const f16x8*)(wP0 + kt * 32);
    const f16x8 b1 = *(const f16x8*)(wP1 + kt * 32);
    acc0 = __builtin_amdgcn_mfma_f32_16x16x32_f16(af.v, b0, acc0, 0, 0, 0);
    acc1 = __builtin_amdgcn_mfma_f32_16x16x32_f16(af.v, b1, acc1, 0, 0, 0);
  }

  // ---- per-head scores (full fp32 path) ----
  const float avS0 = a[w * 64 + nl];
  const float avS1 = a[w * 64 + 16 + nl];
  const float avD0 = a[w * 64 + 32 + nl];
  const float avD1 = a[w * 64 + 48 + nl];

  float si[4], sj[4];
#pragma unroll
  for (int reg = 0; reg < 4; ++reg) {
    si[reg] = acc0[reg] * avS0 + acc1[reg] * avS1;
    sj[reg] = acc0[reg] * avD0 + acc1[reg] * avD1;
#pragma unroll
    for (int off = 1; off < 16; off <<= 1) {
      si[reg] += __shfl_xor(si[reg], off, 64);
      sj[reg] += __shfl_xor(sj[reg], off, 64);
    }
  }
  if (nl == 0) {
    const int base = bb * 2048 + w * 512 + iloc + ig * 4;
#pragma unroll
    for (int reg = 0; reg < 4; ++reg) {
      sIT[base + reg] = si[reg];
      sJT[base + reg] = sj[reg];
    }
  }

  // ---- whT f16 writes (C layout: row m = ig*4+reg -> i, col n = nl -> d) ----
  union { fp16x2 h2[2]; float2 f2; } p0, p1;
  p0.h2[0] = __builtin_amdgcn_cvt_pkrtz(acc0[0], acc0[1]);
  p0.h2[1] = __builtin_amdgcn_cvt_pkrtz(acc0[2], acc0[3]);
  p1.h2[0] = __builtin_amdgcn_cvt_pkrtz(acc1[0], acc1[1]);
  p1.h2[1] = __builtin_amdgcn_cvt_pkrtz(acc1[2], acc1[3]);
  _Float16* wout = whT + (size_t)bb * 128 * 512 + iloc + ig * 4;
  *(float2*)(wout + (size_t)(w * 32 + nl) * 512)      = p0.f2;
  *(float2*)(wout + (size_t)(w * 32 + 16 + nl) * 512) = p1.f2;
}

// ---------------------------------------------------------------------------
// Kernel 3: attention+aggregate (unchanged from round 6). Zero LDS/barriers;
// mask bits in registers; si/WhT fragments direct from L2; MFMA 16x16x32.
// ---------------------------------------------------------------------------
__global__ __launch_bounds__(256, 4) void gat_attn_kernel(
    const unsigned* __restrict__ maskT, const _Float16* __restrict__ whT,
    const float* __restrict__ sIT, const float* __restrict__ sJT,
    float* __restrict__ out) {
  const int tid = threadIdx.x;
  const int b = blockIdx.x;            // 0..31
  const int j0 = blockIdx.y * 16;      // 32 tiles
  const int wv = tid >> 6;             // wave = head
  const int lane = tid & 63;
  const int nl = lane & 15;
  const int ig = lane >> 4;

  const float sj = sJT[b * 2048 + wv * 512 + j0 + nl];

  const unsigned* mP = maskT + ((size_t)b * 512 + j0 + nl) * 16;
  uint4 mA = *(const uint4*)(mP);
  uint4 mB = *(const uint4*)(mP + 4);
  uint4 mC = *(const uint4*)(mP + 8);
  uint4 mD = *(const uint4*)(mP + 12);
  const unsigned mw[16] = {mA.x, mA.y, mA.z, mA.w, mB.x, mB.y, mB.z, mB.w,
                           mC.x, mC.y, mC.z, mC.w, mD.x, mD.y, mD.z, mD.w};

  const _Float16* whP = whT + (size_t)b * 128 * 512 + (size_t)(wv * 32 + nl) * 512 + ig * 8;
  const float* siP = sIT + b * 2048 + wv * 512 + ig * 8;

  f32x4 acc0 = {0.f, 0.f, 0.f, 0.f};
  f32x4 acc1 = {0.f, 0.f, 0.f, 0.f};
  float l = 0.f;

#pragma unroll
  for (int t = 0; t < 8; ++t) {
#pragma unroll
    for (int ks = 0; ks < 2; ++ks) {
      f32x4 sA = *(const f32x4*)(siP + t * 64 + ks * 32);
      f32x4 sB = *(const f32x4*)(siP + t * 64 + ks * 32 + 4);
      const f16x8 bf0 = *(const f16x8*)(whP + t * 64 + ks * 32);
      const f16x8 bf1 = *(const f16x8*)(whP + 16 * 512 + t * 64 + ks * 32);
      const unsigned bits = (mw[t * 2 + ks] >> (ig * 8)) & 0xffu;

      float si[8] = {sA.x, sA.y, sA.z, sA.w, sB.x, sB.y, sB.z, sB.w};
      float p[8];
#pragma unroll
      for (int r = 0; r < 8; ++r) {
        float e = si[r] + sj;
        e = e >= 0.f ? e : NEG_SLOPE * e;
        p[r] = (bits & (1u << r)) ? __expf(e) : 0.f;
      }
      l += ((p[0] + p[1]) + (p[2] + p[3])) + ((p[4] + p[5]) + (p[6] + p[7]));

      union { fp16x2 h2[4]; f16x8 v; } af;
#pragma unroll
      for (int q = 0; q < 4; ++q)
        af.h2[q] = __builtin_amdgcn_cvt_pkrtz(p[2 * q], p[2 * q + 1]);

      acc0 = __builtin_amdgcn_mfma_f32_16x16x32_f16(af.v, bf0, acc0, 0, 0, 0);
      acc1 = __builtin_amdgcn_mfma_f32_16x16x32_f16(af.v, bf1, acc1, 0, 0, 0);
    }
  }

  l += __shfl_xor(l, 16, 64);
  l += __shfl_xor(l, 32, 64);

  float* outB = out + ((size_t)b * 512 + j0) * 128 + wv * 32;
#pragma unroll
  for (int reg = 0; reg < 4; ++reg) {
    const int jr = 4 * ig + reg;
    const float rl = 1.0f / __shfl(l, jr, 64);
    outB[(size_t)jr * 128 + nl]      = acc0[reg] * rl;
    outB[(size_t)jr * 128 + 16 + nl] = acc1[reg] * rl;
  }
}

extern "C" void kernel_launch(void* const* d_in, const int* in_sizes, int n_in,
                              void* d_out, int out_size, void* d_ws, size_t ws_size,
                              hipStream_t stream) {
  const float* h = (const float*)d_in[0];     // (32, 512, 128)
  const float* adj = (const float*)d_in[1];   // (32, 512, 512)
  const float* W = (const float*)d_in[2];     // (128, 128)
  const float* a = (const float*)d_in[3];     // (4, 64)
  float* out = (float*)d_out;                 // (32, 512, 128)

  _Float16* whT = (_Float16*)d_ws;                      // 4 MB
  float* sIT = (float*)(whT + (size_t)32 * 128 * 512);  // 256 KB
  float* sJT = sIT + (size_t)32 * 4 * 512;              // 256 KB
  unsigned* maskT = (unsigned*)(sJT + (size_t)32 * 4 * 512);  // 1 MB
  _Float16* wTf16 = (_Float16*)(maskT + (size_t)32 * 512 * 16);  // 32 KB

  gat_mask_kernel<<<dim3(32, 8, 4), dim3(256), 0, stream>>>(adj, maskT, W, wTf16);
  gat_wh_mfma<<<dim3(1024), dim3(256), 0, stream>>>(h, wTf16, a, whT, sIT, sJT);
  gat_attn_kernel<<<dim3(32, 32), dim3(256), 0, stream>>>(maskT, whT, sIT, sJT, out);
}